// Round 1
// 203.931 us; speedup vs baseline: 1.0228x; 1.0228x over previous
//
#include <hip/hip_runtime.h>
#include <stdint.h>

#define T_DIM 2048
#define V_DIM 1024
#define B_DIM 8
#define NT 16            // T_DIM/128

typedef unsigned int u32;
typedef unsigned short u16;
typedef __attribute__((ext_vector_type(8))) short s16x8;
typedef __attribute__((ext_vector_type(4))) float f32x4;

__device__ __forceinline__ u16 f2bf(float x) {
  u32 u = __builtin_bit_cast(u32, x);
  u = u + 0x7FFFu + ((u >> 16) & 1u);   // round-to-nearest-even
  return (u16)(u >> 16);
}

// async global->LDS, 16B per lane (m97 pattern)
#define GLD16(gp, lp) __builtin_amdgcn_global_load_lds( \
    (const __attribute__((address_space(1))) u32*)(gp), \
    (__attribute__((address_space(3))) u32*)(lp), 16, 0, 0)

// ---------------------------------------------------------------------------
// Legacy 128x128 kernel — kept for MODE 0 (small V x V GEMM) only.
// ---------------------------------------------------------------------------
template<int MODE, bool F32OUT>
__global__ void __launch_bounds__(256, 2)
gemm_bt(const u16* __restrict__ A, int lda, long long batchA,
        const u16* __restrict__ Bt, int ldb, long long batchB,
        void* __restrict__ Cv, int ldc, long long batchC,
        int K, float bias)
{
  int bn, bm, bz;
  if (MODE == 0) {
    bn = blockIdx.x; bm = blockIdx.y; bz = blockIdx.z;
  } else if (MODE == 1) {
    int lam = blockIdx.x;
    int tau = lam >> 3; bz = lam & 7;
    int b = NT - 1, off = 0;
    while (tau >= off + (NT - b)) { off += NT - b; b--; }
    bn = b; bm = b + (tau - off);
  } else {
    int lam = blockIdx.x;
    bm = (NT - 1) - (lam >> 6);
    bn = (lam >> 3) & 7;
    bz = lam & 7;
  }
  const u16* Ab = A + (long long)bz * batchA;
  const u16* Bb = Bt + (long long)bz * batchB;
  int m0 = bm * 128, n0 = bn * 128;
  int kmax = K;
  if (MODE == 1) { int kl = (bn + 1) * 128; kmax = kl < K ? kl : K; }
  if (MODE == 2) { int kl = (bm + 1) * 128; kmax = kl < K ? kl : K; }

  __shared__ u16 As[128 * 64];
  __shared__ u16 Bs[128 * 64];

  int tid = threadIdx.x;
  int lane = tid & 63;
  int wid = tid >> 6;
  int wm = wid >> 1, wn = wid & 1;

  f32x4 acc[4][4] = {};

  int r0 = tid >> 3;
  int gcol = (((tid & 7) - r0) & 7) * 8;
  const u16* ga = Ab + (long long)(m0 + r0) * lda + gcol;
  const u16* gb = Bb + (long long)(n0 + r0) * ldb + gcol;
  u16* la = As + tid * 8;
  u16* lb = Bs + tid * 8;
  long long lda32 = (long long)32 * lda;
  long long ldb32 = (long long)32 * ldb;

  int rm = lane & 15;
  int q = lane >> 4;

  for (int k0 = 0; k0 < kmax; k0 += 64) {
#pragma unroll
    for (int i = 0; i < 4; i++)
      GLD16(ga + k0 + i * lda32, la + i * 2048);
#pragma unroll
    for (int i = 0; i < 4; i++)
      GLD16(gb + k0 + i * ldb32, lb + i * 2048);
    __syncthreads();
#pragma unroll
    for (int ks = 0; ks < 2; ks++) {
      s16x8 af[4], bfv[4];
#pragma unroll
      for (int mi = 0; mi < 4; mi++) {
        int row = wm * 64 + mi * 16 + rm;
        int p = ((ks * 4 + q) + row) & 7;
        af[mi] = *(const s16x8*)&As[row * 64 + p * 8];
      }
#pragma unroll
      for (int ni = 0; ni < 4; ni++) {
        int row = wn * 64 + ni * 16 + rm;
        int p = ((ks * 4 + q) + row) & 7;
        bfv[ni] = *(const s16x8*)&Bs[row * 64 + p * 8];
      }
#pragma unroll
      for (int mi = 0; mi < 4; mi++)
#pragma unroll
        for (int ni = 0; ni < 4; ni++)
          acc[mi][ni] = __builtin_amdgcn_mfma_f32_16x16x32_bf16(
              af[mi], bfv[ni], acc[mi][ni], 0, 0, 0);
    }
    __syncthreads();
  }

  int col = lane & 15;
  int rq = (lane >> 4) * 4;
#pragma unroll
  for (int mi = 0; mi < 4; mi++) {
#pragma unroll
    for (int ni = 0; ni < 4; ni++) {
      int lr = wm * 64 + mi * 16 + rq;
      int lc = wn * 64 + ni * 16 + col;
#pragma unroll
      for (int rr = 0; rr < 4; rr++) {
        float val = acc[mi][ni][rr];
        if (MODE == 1 && (n0 + lc) > (m0 + lr + rr)) val = 0.f;
        long long off = (long long)(m0 + lr + rr) * ldc + (n0 + lc);
        if (F32OUT) {
          float* C = (float*)Cv + (long long)bz * batchC;
          C[off] = val + bias;
        } else {
          u16* C = (u16*)Cv + (long long)bz * batchC;
          C[off] = f2bf(val);
        }
      }
    }
  }
}

// ---------------------------------------------------------------------------
// gemm8: 8-wave (512-thread) pipelined GEMM, tile 128(M) x 256(N), BK=64.
// C[m,n] = sum_k A[m,k] * Bt[n,k], bf16 in, f32 accum.
// Waves 2(M) x 4(N), per-wave 64x64 output (4x4 16x16x32 fragments).
// LDS: 3 K-tile buffers x (A 16KB + B 32KB) = 144 KiB, prefetch distance 2,
// steady-state wait = vmcnt(6) (6 loads of tile kt+1 stay in flight across
// barriers; never vmcnt(0) in the main loop). Raw s_barrier, setprio around
// MFMA clusters. Rotation swizzle (slot p of row r holds chunk (p-r)&7) keeps
// ds_read_b128 bank-conflict-free; staging pre-swizzles the global source.
// MODE 1: A = tril(G * P^T). M-tiles of 128 (m=0..15), N-tiles of 256
//         (n=0..7), tile iff n <= m>>1, kmax=(n+1)*256 (extra K multiplies
//         exact zeros of P => bit-identical). bf16 out, tril mask. LPT: n desc.
// MODE 2: out = A * Yt^T + bias. m=0..15, n=0..3, kmax=(m+1)*128. f32 out.
//         LPT: m desc.
// ---------------------------------------------------------------------------
#define LDSB 24576          // elements per buffer: A 8192 + B 16384
#define FENCE() asm volatile("" ::: "memory")

template<int MODE>
__global__ void __launch_bounds__(512, 2)
gemm8(const u16* __restrict__ Ag, int lda, long long batchA,
      const u16* __restrict__ Btg, int ldb, long long batchB,
      void* __restrict__ Cv, int ldc, long long batchC,
      float bias, int lnb)
{
  int lam = blockIdx.x;
  int bz = lam & ((1 << lnb) - 1);
  int tau = lam >> lnb;
  int m, n;
  if (MODE == 1) {
    int nn = 7, off = 0;                 // n descending = heavy first (LPT)
    while (tau >= off + (16 - 2 * nn)) { off += 16 - 2 * nn; nn--; }
    n = nn; m = 2 * nn + (tau - off);
  } else {
    m = 15 - (tau >> 2);                 // m descending = heavy first (LPT)
    n = tau & 3;
  }
  const int m0 = m * 128, n0 = n * 256;
  const int nk = (MODE == 1) ? (n + 1) * 4 : (m + 1) * 2;   // 64-K tiles, >= 2

  const u16* __restrict__ Ab = Ag + (long long)bz * batchA;
  const u16* __restrict__ Bb = Btg + (long long)bz * batchB;

  __shared__ u16 lds[3 * LDSB];          // 144 KiB

  const int tid = threadIdx.x;
  const int lane = tid & 63;
  const int wid = tid >> 6;
  const int wm = wid >> 2, wn = wid & 3;

  // ---- staging descriptors (per-pass global ptr + linear LDS offset) ----
  // pass f: row r=f>>3, slot p=f&7 holds logical chunk (p-r)&7.
  const u16* ga[2]; int la_[2];
#pragma unroll
  for (int i = 0; i < 2; i++) {
    int f = i * 512 + tid, r = f >> 3, c = ((f & 7) - r) & 7;
    ga[i] = Ab + (long long)(m0 + r) * lda + c * 8;
    la_[i] = f * 8;
  }
  const u16* gb[4]; int lb_[4];
#pragma unroll
  for (int i = 0; i < 4; i++) {
    int f = i * 512 + tid, r = f >> 3, c = ((f & 7) - r) & 7;
    gb[i] = Bb + (long long)(n0 + r) * ldb + c * 8;
    lb_[i] = 8192 + f * 8;
  }

  // ---- fragment LDS offsets ----
  const int rm = lane & 15, q = lane >> 4;
  int aoff[4][2], boff[4][2];
#pragma unroll
  for (int mi = 0; mi < 4; mi++)
#pragma unroll
    for (int ks = 0; ks < 2; ks++) {
      int row = wm * 64 + mi * 16 + rm;
      aoff[mi][ks] = row * 64 + (((ks * 4 + q) + row) & 7) * 8;
    }
#pragma unroll
  for (int ni = 0; ni < 4; ni++)
#pragma unroll
    for (int ks = 0; ks < 2; ks++) {
      int row = wn * 64 + ni * 16 + rm;
      boff[ni][ks] = 8192 + row * 64 + (((ks * 4 + q) + row) & 7) * 8;
    }

  f32x4 acc[4][4] = {};

  // ---- prologue: stage K-tiles 0 and 1 (nk >= 2 always) ----
#pragma unroll
  for (int i = 0; i < 2; i++) GLD16(ga[i], &lds[la_[i]]);
#pragma unroll
  for (int i = 0; i < 4; i++) GLD16(gb[i], &lds[lb_[i]]);
#pragma unroll
  for (int i = 0; i < 2; i++) GLD16(ga[i] + 64, &lds[LDSB + la_[i]]);
#pragma unroll
  for (int i = 0; i < 4; i++) GLD16(gb[i] + 64, &lds[LDSB + lb_[i]]);

  int cb = 0;                                   // current buffer base (elems)
  for (int kt = 0; kt < nk; ++kt) {
    // tile kt ready; keep tile kt+1's 6 loads in flight (counted vmcnt, T4)
    if (kt + 1 < nk) asm volatile("s_waitcnt vmcnt(6)" ::: "memory");
    else             asm volatile("s_waitcnt vmcnt(0)" ::: "memory");
    __builtin_amdgcn_s_barrier();
    FENCE();

    const u16* Abuf = &lds[cb];
    int pb = cb + 2 * LDSB; if (pb >= 3 * LDSB) pb -= 3 * LDSB;
    const bool pf = (kt + 2) < nk;
    const int pk = (kt + 2) * 64;

    // ---- phase 0: read A frags + B frags (n0,n1); prefetch A + first B ----
    s16x8 af[4][2], bf0[2][2];
#pragma unroll
    for (int mi = 0; mi < 4; mi++)
#pragma unroll
      for (int ks = 0; ks < 2; ks++)
        af[mi][ks] = *(const s16x8*)&Abuf[aoff[mi][ks]];
#pragma unroll
    for (int ni = 0; ni < 2; ni++)
#pragma unroll
      for (int ks = 0; ks < 2; ks++)
        bf0[ni][ks] = *(const s16x8*)&Abuf[boff[ni][ks]];
    if (pf) {
      GLD16(ga[0] + pk, &lds[pb + la_[0]]);
      GLD16(ga[1] + pk, &lds[pb + la_[1]]);
      GLD16(gb[0] + pk, &lds[pb + lb_[0]]);
    }
    __builtin_amdgcn_s_barrier();
    FENCE();
    __builtin_amdgcn_s_setprio(1);
#pragma unroll
    for (int ks = 0; ks < 2; ks++)
#pragma unroll
      for (int mi = 0; mi < 4; mi++)
#pragma unroll
        for (int ni = 0; ni < 2; ni++)
          acc[mi][ni] = __builtin_amdgcn_mfma_f32_16x16x32_bf16(
              af[mi][ks], bf0[ni][ks], acc[mi][ni], 0, 0, 0);
    __builtin_amdgcn_s_setprio(0);
    __builtin_amdgcn_s_barrier();
    FENCE();

    // ---- phase 1: read B frags (n2,n3); prefetch remaining B ----
    s16x8 bf1[2][2];
#pragma unroll
    for (int ni = 0; ni < 2; ni++)
#pragma unroll
      for (int ks = 0; ks < 2; ks++)
        bf1[ni][ks] = *(const s16x8*)&Abuf[boff[ni + 2][ks]];
    if (pf) {
      GLD16(gb[1] + pk, &lds[pb + lb_[1]]);
      GLD16(gb[2] + pk, &lds[pb + lb_[2]]);
      GLD16(gb[3] + pk, &lds[pb + lb_[3]]);
    }
    __builtin_amdgcn_s_barrier();
    FENCE();
    __builtin_amdgcn_s_setprio(1);
#pragma unroll
    for (int ks = 0; ks < 2; ks++)
#pragma unroll
      for (int mi = 0; mi < 4; mi++)
#pragma unroll
        for (int ni = 0; ni < 2; ni++)
          acc[mi][ni + 2] = __builtin_amdgcn_mfma_f32_16x16x32_bf16(
              af[mi][ks], bf1[ni][ks], acc[mi][ni + 2], 0, 0, 0);
    __builtin_amdgcn_s_setprio(0);
    // next iteration's wait+barrier seals this buffer before reuse
    cb += LDSB; if (cb >= 3 * LDSB) cb = 0;
  }

  // ---- epilogue ----
  const int col = lane & 15, rq = (lane >> 4) * 4;
  if (MODE == 2) {
    float* C = (float*)Cv + (long long)bz * batchC;
#pragma unroll
    for (int mi = 0; mi < 4; mi++) {
      int lr = m0 + wm * 64 + mi * 16 + rq;
#pragma unroll
      for (int ni = 0; ni < 4; ni++) {
        int lc = n0 + wn * 64 + ni * 16 + col;
#pragma unroll
        for (int rr = 0; rr < 4; rr++)
          C[(long long)(lr + rr) * ldc + lc] = acc[mi][ni][rr] + bias;
      }
    }
  } else {
    u16* C = (u16*)Cv + (long long)bz * batchC;
#pragma unroll
    for (int mi = 0; mi < 4; mi++) {
      int lr = m0 + wm * 64 + mi * 16 + rq;
#pragma unroll
      for (int ni = 0; ni < 4; ni++) {
        int lc = n0 + wn * 64 + ni * 16 + col;
#pragma unroll
        for (int rr = 0; rr < 4; rr++) {
          float val = acc[mi][ni][rr];
          if (lc > lr + rr) val = 0.f;           // causal mask
          C[(long long)(lr + rr) * ldc + lc] = f2bf(val);
        }
      }
    }
  }
}

// ---------------------------------------------------------------------------
// prep: z<2: transpose+cast VxV fp32 -> bf16 (dst[i][o]=src[o][i]);
//       z==2: straight cast of Wv
// ---------------------------------------------------------------------------
__global__ void prep_weights(const float* __restrict__ Wq, u16* __restrict__ WqT,
                             const float* __restrict__ Wk, u16* __restrict__ WkT,
                             const float* __restrict__ Wv, u16* __restrict__ Wvb)
{
  int z = blockIdx.z;
  if (z == 2) {
    int bx = blockIdx.y * 32 + blockIdx.x;
    int i = bx * 1024 + threadIdx.y * 32 + threadIdx.x;
#pragma unroll
    for (int k = 0; k < 4; k++) Wvb[i + k * 256] = f2bf(Wv[i + k * 256]);
    return;
  }
  const float* src = z ? Wk : Wq;
  u16* dst = z ? WkT : WqT;
  __shared__ float tile[32][33];
  int x0 = blockIdx.x * 32, y0 = blockIdx.y * 32;
  int tx = threadIdx.x, ty = threadIdx.y;
#pragma unroll
  for (int k = 0; k < 4; k++)
    tile[ty + k * 8][tx] = src[(long long)(y0 + ty + k * 8) * V_DIM + x0 + tx];
  __syncthreads();
#pragma unroll
  for (int k = 0; k < 4; k++)
    dst[(long long)(x0 + ty + k * 8) * V_DIM + y0 + tx] = f2bf(tile[tx][ty + k * 8]);
}

// P[s][u] = v[s-u] for u<=s else 0  (T x T bf16), 16B stores
__global__ void build_p(const float* __restrict__ v, u16* __restrict__ P)
{
  int gid = blockIdx.x * 256 + threadIdx.x;
  int e0 = gid * 8;
  int s = e0 >> 11, u0 = e0 & 2047;
  s16x8 o;
#pragma unroll
  for (int k = 0; k < 8; k++) {
    int u = u0 + k;
    o[k] = (short)((u <= s) ? f2bf(v[s - u]) : (u16)0);
  }
  *(s16x8*)&P[e0] = o;
}

// merged gather: bx<T: G[z][t][u]=M[idx[t]][idx[u]]; else Yt[z][j][s]=Wv[j][idx[s]]
__global__ void __launch_bounds__(256)
gather_gy(const int* __restrict__ idx, const u16* __restrict__ Mb,
          const u16* __restrict__ Wvb, u16* __restrict__ G,
          u16* __restrict__ Yt, int b0)
{
  int bx = blockIdx.x, z = blockIdx.y;
  const int* idxrow = idx + (long long)(b0 + z) * T_DIM;
  __shared__ u16 Row[V_DIM];
  int tid = threadIdx.x;
  const u32* src;
  u16* dst;
  if (bx < T_DIM) {
    src = (const u32*)(Mb + (long long)idxrow[bx] * V_DIM);
    dst = G + ((long long)z * T_DIM + bx) * T_DIM;
  } else {
    src = (const u32*)(Wvb + (long long)(bx - T_DIM) * V_DIM);
    dst = Yt + ((long long)z * V_DIM + (bx - T_DIM)) * T_DIM;
  }
  u32* dstl = (u32*)Row;
  dstl[tid] = src[tid];
  dstl[tid + 256] = src[tid + 256];
  __syncthreads();
  int s0 = tid * 8;
  int4 i0 = *(const int4*)&idxrow[s0];
  int4 i1 = *(const int4*)&idxrow[s0 + 4];
  s16x8 o;
  o[0] = (short)Row[i0.x]; o[1] = (short)Row[i0.y];
  o[2] = (short)Row[i0.z]; o[3] = (short)Row[i0.w];
  o[4] = (short)Row[i1.x]; o[5] = (short)Row[i1.y];
  o[6] = (short)Row[i1.z]; o[7] = (short)Row[i1.w];
  *(s16x8*)&dst[s0] = o;
}

// ---------------------------------------------------------------------------
extern "C" void kernel_launch(void* const* d_in, const int* in_sizes, int n_in,
                              void* d_out, int out_size, void* d_ws, size_t ws_size,
                              hipStream_t stream)
{
  const int*   idx = (const int*)d_in[0];
  const float* v   = (const float*)d_in[1];
  const float* Wk  = (const float*)d_in[2];
  const float* Wq  = (const float*)d_in[3];
  const float* Wv  = (const float*)d_in[4];
  float* out = (float*)d_out;

  char* p = (char*)d_ws;
  const size_t SZ_VV = (size_t)V_DIM * V_DIM * 2;   // 2 MB bf16
  const size_t SZ_TT = (size_t)T_DIM * T_DIM * 2;   // 8 MB bf16
  const size_t SZ_VT = (size_t)V_DIM * T_DIM * 2;   // 4 MB bf16
  u16* WqT = (u16*)p; p += SZ_VV;
  u16* WkT = (u16*)p; p += SZ_VV;
  u16* Wvb = (u16*)p; p += SZ_VV;
  u16* Mb  = (u16*)p; p += SZ_VV;
  u16* P   = (u16*)p; p += SZ_TT;
  size_t used = (size_t)(p - (char*)d_ws);
  size_t per = 2 * SZ_TT + SZ_VT;                    // G + A + Yt per batch
  int nb = 8;
  while (nb > 1 && used + (size_t)nb * per > ws_size) nb >>= 1;
  u16* G    = (u16*)p; p += (size_t)nb * SZ_TT;
  u16* Abuf = (u16*)p; p += (size_t)nb * SZ_TT;
  u16* Yt   = (u16*)p;
  int lnb = (nb == 8) ? 3 : (nb == 4) ? 2 : (nb == 2) ? 1 : 0;

  prep_weights<<<dim3(32, 32, 3), dim3(32, 8), 0, stream>>>(Wq, WqT, Wk, WkT, Wv, Wvb);
  build_p<<<2048, 256, 0, stream>>>(v, P);
  // M = Wq^T * Wk  [V,V]
  gemm_bt<0, false><<<dim3(V_DIM / 128, V_DIM / 128, 1), 256, 0, stream>>>(
      WqT, V_DIM, 0, WkT, V_DIM, 0, Mb, V_DIM, 0, V_DIM, 0.f);

  for (int b0 = 0; b0 < B_DIM; b0 += nb) {
    gather_gy<<<dim3(T_DIM + V_DIM, nb), 256, 0, stream>>>(idx, Mb, Wvb, G, Yt, b0);
    // A = tril(G * P^T): 72 tiles (128x256) x nb, n-desc LPT, pipelined 8-wave
    gemm8<1><<<dim3(72 * nb), 512, 0, stream>>>(
        G, T_DIM, (long long)T_DIM * T_DIM, P, T_DIM, 0,
        Abuf, T_DIM, (long long)T_DIM * T_DIM, 0.f, lnb);
    // out = A * Yt^T + 0.001: 64 tiles (128x256) x nb, m-desc LPT
    gemm8<2><<<dim3(64 * nb), 512, 0, stream>>>(
        Abuf, T_DIM, (long long)T_DIM * T_DIM, Yt, T_DIM, (long long)V_DIM * T_DIM,
        out + (long long)b0 * T_DIM * V_DIM, V_DIM, (long long)T_DIM * V_DIM,
        0.001f, lnb);
  }
}